// Round 1
// baseline (3112.586 us; speedup 1.0000x reference)
//
#include <hip/hip_runtime.h>
#include <hip/hip_bf16.h>

#define NB 2
#define NS 2048
#define ND 1024
#define NH 16
#define NDK 64
#define NBH (NB * NH)

// ---------------------------------------------------------------------------
// Kernel 1: combined mask  comb = (attn_mask==1) ? -1 : (1 + 0.5*causal)
// Sentinel: negative => masked (valid scale is always >= 1.0)
// ---------------------------------------------------------------------------
__global__ void mask_combine_kernel(const int* __restrict__ am,
                                    const float* __restrict__ cm,
                                    float* __restrict__ outc) {
    int i = (blockIdx.x * 256 + threadIdx.x) * 4;
    int4 a = *reinterpret_cast<const int4*>(am + i);
    float4 c = *reinterpret_cast<const float4*>(cm + i);
    float4 r;
    r.x = (a.x == 1) ? -1.0f : fmaf(0.5f, c.x, 1.0f);
    r.y = (a.y == 1) ? -1.0f : fmaf(0.5f, c.y, 1.0f);
    r.z = (a.z == 1) ? -1.0f : fmaf(0.5f, c.z, 1.0f);
    r.w = (a.w == 1) ? -1.0f : fmaf(0.5f, c.w, 1.0f);
    *reinterpret_cast<float4*>(outc + i) = r;
}

// ---------------------------------------------------------------------------
// Kernel 2: C = X @ W^T + bias.  X [4096,1024] row-major, W [1024,1024]
// row-major (so both operands K-contiguous). BM=BN=64, BK=16, 256 threads,
// 4x4 micro-tile per thread. HEADS=1 writes [B,H,S,DK] layout.
// ---------------------------------------------------------------------------
template <int HEADS>
__global__ __launch_bounds__(256) void proj_kernel(const float* __restrict__ X,
                                                   const float* __restrict__ W,
                                                   const float* __restrict__ bias,
                                                   float* __restrict__ out) {
    __shared__ __align__(16) float As[16][68];  // [k][m], pad 68 keeps 16B align
    __shared__ __align__(16) float Bs[16][68];  // [k][n]
    const int tid = threadIdx.x;
    const int tx = tid & 15, ty = tid >> 4;
    const int gm0 = blockIdx.y * 64, gn0 = blockIdx.x * 64;
    const int lrow = tid >> 2;           // 0..63 tile row for staging
    const int lcg = (tid & 3) * 4;       // 0,4,8,12 k-subcolumn for staging
    const float* xp = X + (size_t)(gm0 + lrow) * ND + lcg;
    const float* wp = W + (size_t)(gn0 + lrow) * ND + lcg;
    float acc[4][4] = {};
    for (int k0 = 0; k0 < ND; k0 += 16) {
        float4 av = *reinterpret_cast<const float4*>(xp + k0);
        float4 bv = *reinterpret_cast<const float4*>(wp + k0);
        __syncthreads();
        As[lcg + 0][lrow] = av.x;
        As[lcg + 1][lrow] = av.y;
        As[lcg + 2][lrow] = av.z;
        As[lcg + 3][lrow] = av.w;
        Bs[lcg + 0][lrow] = bv.x;
        Bs[lcg + 1][lrow] = bv.y;
        Bs[lcg + 2][lrow] = bv.z;
        Bs[lcg + 3][lrow] = bv.w;
        __syncthreads();
#pragma unroll
        for (int k = 0; k < 16; ++k) {
            float4 a4 = *reinterpret_cast<const float4*>(&As[k][ty * 4]);
            float4 b4 = *reinterpret_cast<const float4*>(&Bs[k][tx * 4]);
            const float* a = reinterpret_cast<const float*>(&a4);
            const float* b = reinterpret_cast<const float*>(&b4);
#pragma unroll
            for (int i = 0; i < 4; ++i)
#pragma unroll
                for (int j = 0; j < 4; ++j) acc[i][j] = fmaf(a[i], b[j], acc[i][j]);
        }
    }
#pragma unroll
    for (int i = 0; i < 4; ++i) {
        const int m = gm0 + ty * 4 + i;
#pragma unroll
        for (int j = 0; j < 4; ++j) {
            const int n = gn0 + tx * 4 + j;
            float val = acc[i][j] + bias[n];
            if (HEADS) {
                const int b_ = m >> 11, s_ = m & (NS - 1);
                const int h_ = n >> 6, dk = n & (NDK - 1);
                out[(((size_t)(b_ * NH + h_)) * NS + s_) * NDK + dk] = val;
            } else {
                out[(size_t)m * ND + n] = val;
            }
        }
    }
}

// ---------------------------------------------------------------------------
// Kernel 3: flash attention, fp32, one thread per query row.
// K/V tiles (16 x 64) staged in LDS, read wave-uniform (broadcast).
// Masked entries contribute exactly 0 (matches fp32 underflow of exp(-1e9)).
// ---------------------------------------------------------------------------
__global__ __launch_bounds__(128) void flash_kernel(const float* __restrict__ Q,
                                                    const float* __restrict__ K,
                                                    const float* __restrict__ V,
                                                    const float* __restrict__ comb,
                                                    float* __restrict__ attnOut,
                                                    float* __restrict__ concatOut) {
    __shared__ __align__(16) float Kt[16 * 64];
    __shared__ __align__(16) float Vt[16 * 64];
    const int tid = threadIdx.x;
    const int bh = blockIdx.y;                // 0..31
    const int r = blockIdx.x * 128 + tid;     // query row in [0,S)
    const int b_ = bh >> 4, h_ = bh & 15;

    const float* qrow = Q + ((size_t)bh * NS + r) * NDK;
    float4 q[16];
#pragma unroll
    for (int i = 0; i < 16; ++i) q[i] = *reinterpret_cast<const float4*>(qrow + i * 4);
    float4 o[16];
#pragma unroll
    for (int i = 0; i < 16; ++i) o[i] = make_float4(0.f, 0.f, 0.f, 0.f);
    float mrun = -1e30f, lrun = 0.f;

    const float* Kbase = K + (size_t)bh * NS * NDK;
    const float* Vbase = V + (size_t)bh * NS * NDK;
    const float* crow = comb + (size_t)r * NS;

    for (int kt = 0; kt < NS; kt += 16) {
        __syncthreads();
        {
            const float4* ks = reinterpret_cast<const float4*>(Kbase + (size_t)kt * NDK);
            const float4* vs = reinterpret_cast<const float4*>(Vbase + (size_t)kt * NDK);
            float4* kd = reinterpret_cast<float4*>(Kt);
            float4* vd = reinterpret_cast<float4*>(Vt);
            kd[tid] = ks[tid];
            kd[tid + 128] = ks[tid + 128];
            vd[tid] = vs[tid];
            vd[tid + 128] = vs[tid + 128];
        }
        __syncthreads();

        float cm_[16];
        *reinterpret_cast<float4*>(&cm_[0]) = *reinterpret_cast<const float4*>(crow + kt);
        *reinterpret_cast<float4*>(&cm_[4]) = *reinterpret_cast<const float4*>(crow + kt + 4);
        *reinterpret_cast<float4*>(&cm_[8]) = *reinterpret_cast<const float4*>(crow + kt + 8);
        *reinterpret_cast<float4*>(&cm_[12]) = *reinterpret_cast<const float4*>(crow + kt + 12);

        float lg[16];
        float tmax = -1e30f;
#pragma unroll
        for (int jj = 0; jj < 16; ++jj) {
            const float4* kk = reinterpret_cast<const float4*>(Kt + jj * 64);
            float s = 0.f;
#pragma unroll
            for (int d4 = 0; d4 < 16; ++d4) {
                float4 kv = kk[d4];
                s = fmaf(q[d4].x, kv.x, s);
                s = fmaf(q[d4].y, kv.y, s);
                s = fmaf(q[d4].z, kv.z, s);
                s = fmaf(q[d4].w, kv.w, s);
            }
            s *= 0.125f;  // 1/sqrt(64)
            const float sc = cm_[jj];
            lg[jj] = (sc < 0.f) ? -1e30f : s * sc;
            tmax = fmaxf(tmax, lg[jj]);
        }
        const float mnew = fmaxf(mrun, tmax);
        const float scale = __expf(mrun - mnew);  // 1 if nothing unmasked yet
        lrun *= scale;
#pragma unroll
        for (int i = 0; i < 16; ++i) {
            o[i].x *= scale;
            o[i].y *= scale;
            o[i].z *= scale;
            o[i].w *= scale;
        }
#pragma unroll
        for (int jj = 0; jj < 16; ++jj) {
            const float p = (lg[jj] <= -1e29f) ? 0.f : __expf(lg[jj] - mnew);
            lrun += p;
            const float4* vv = reinterpret_cast<const float4*>(Vt + jj * 64);
#pragma unroll
            for (int d4 = 0; d4 < 16; ++d4) {
                float4 x = vv[d4];
                o[d4].x = fmaf(p, x.x, o[d4].x);
                o[d4].y = fmaf(p, x.y, o[d4].y);
                o[d4].z = fmaf(p, x.z, o[d4].z);
                o[d4].w = fmaf(p, x.w, o[d4].w);
            }
        }
        mrun = mnew;
    }

    const float inv = 1.0f / lrun;
    float* aout = attnOut + ((size_t)bh * NS + r) * NDK;
    float* cout = concatOut + ((size_t)b_ * NS + r) * ND + h_ * NDK;
#pragma unroll
    for (int i = 0; i < 16; ++i) {
        float4 x = o[i];
        x.x *= inv;
        x.y *= inv;
        x.z *= inv;
        x.w *= inv;
        *reinterpret_cast<float4*>(aout + i * 4) = x;
        *reinterpret_cast<float4*>(cout + i * 4) = x;
    }
}

// ---------------------------------------------------------------------------
extern "C" void kernel_launch(void* const* d_in, const int* in_sizes, int n_in,
                              void* d_out, int out_size, void* d_ws, size_t ws_size,
                              hipStream_t stream) {
    const float* q = (const float*)d_in[0];
    const float* k = (const float*)d_in[1];
    const float* v = (const float*)d_in[2];
    const int* am = (const int*)d_in[3];
    const float* cm = (const float*)d_in[4];
    const float* Wq = (const float*)d_in[5];
    const float* bq = (const float*)d_in[6];
    const float* Wk = (const float*)d_in[7];
    const float* bk = (const float*)d_in[8];
    const float* Wv = (const float*)d_in[9];
    const float* bv = (const float*)d_in[10];
    const float* Wo = (const float*)d_in[11];
    const float* bo = (const float*)d_in[12];

    float* out = (float*)d_out;                          // [B,S,D]
    float* attn_out = out + (size_t)NB * NS * ND;        // [B,H,S,DK]

    float* ws = (float*)d_ws;
    float* Qh = ws;                   // [B,H,S,DK] 4194304
    float* Kh = ws + 4194304;         // 4194304
    float* Vh = ws + 8388608;         // 4194304
    float* CC = ws + 12582912;        // concat [B,S,D] 4194304
    float* CB = ws + 16777216;        // combined mask [S,S] 4194304

    hipLaunchKernelGGL(mask_combine_kernel, dim3(4096), dim3(256), 0, stream, am, cm, CB);
    hipLaunchKernelGGL((proj_kernel<1>), dim3(16, 64), dim3(256), 0, stream, q, Wq, bq, Qh);
    hipLaunchKernelGGL((proj_kernel<1>), dim3(16, 64), dim3(256), 0, stream, k, Wk, bk, Kh);
    hipLaunchKernelGGL((proj_kernel<1>), dim3(16, 64), dim3(256), 0, stream, v, Wv, bv, Vh);
    hipLaunchKernelGGL(flash_kernel, dim3(16, 32), dim3(128), 0, stream, Qh, Kh, Vh, CB,
                       attn_out, CC);
    hipLaunchKernelGGL((proj_kernel<0>), dim3(16, 64), dim3(256), 0, stream, CC, Wo, bo, out);
}

// Round 2
// 605.681 us; speedup vs baseline: 5.1390x; 5.1390x over previous
//
#include <hip/hip_runtime.h>
#include <hip/hip_bf16.h>

#define NB 2
#define NS 2048
#define ND 1024
#define NH 16
#define NDK 64

using bf16_t = __hip_bfloat16;
typedef __attribute__((ext_vector_type(8))) short bf16x8;
typedef __attribute__((ext_vector_type(4))) float f32x4;

static __device__ __forceinline__ unsigned short f2bf(float f) {
    __hip_bfloat16 h = __float2bfloat16(f);
    return *reinterpret_cast<unsigned short*>(&h);
}

// ---------------------------------------------------------------------------
// Kernel 1: combined mask  comb = (attn_mask==1) ? -1 : (1 + 0.5*causal)
// ---------------------------------------------------------------------------
__global__ void mask_combine_kernel(const int* __restrict__ am,
                                    const float* __restrict__ cm,
                                    float* __restrict__ outc) {
    int i = (blockIdx.x * 256 + threadIdx.x) * 4;
    int4 a = *reinterpret_cast<const int4*>(am + i);
    float4 c = *reinterpret_cast<const float4*>(cm + i);
    float4 r;
    r.x = (a.x == 1) ? -1.0f : fmaf(0.5f, c.x, 1.0f);
    r.y = (a.y == 1) ? -1.0f : fmaf(0.5f, c.y, 1.0f);
    r.z = (a.z == 1) ? -1.0f : fmaf(0.5f, c.z, 1.0f);
    r.w = (a.w == 1) ? -1.0f : fmaf(0.5f, c.w, 1.0f);
    *reinterpret_cast<float4*>(outc + i) = r;
}

// ---------------------------------------------------------------------------
// Kernel 2: C = X @ W^T + bias (fp32 accum). MODE 0: fp32 [M][N] out.
// MODE 1: bf16 out in [B,H,S,DK] layout.
// ---------------------------------------------------------------------------
template <int MODE>
__global__ __launch_bounds__(256) void proj_kernel(const float* __restrict__ X,
                                                   const float* __restrict__ W,
                                                   const float* __restrict__ bias,
                                                   void* __restrict__ outp) {
    __shared__ __align__(16) float As[16][68];
    __shared__ __align__(16) float Bs[16][68];
    const int tid = threadIdx.x;
    const int tx = tid & 15, ty = tid >> 4;
    const int gm0 = blockIdx.y * 64, gn0 = blockIdx.x * 64;
    const int lrow = tid >> 2;
    const int lcg = (tid & 3) * 4;
    const float* xp = X + (size_t)(gm0 + lrow) * ND + lcg;
    const float* wp = W + (size_t)(gn0 + lrow) * ND + lcg;
    float acc[4][4] = {};
    for (int k0 = 0; k0 < ND; k0 += 16) {
        float4 av = *reinterpret_cast<const float4*>(xp + k0);
        float4 bv = *reinterpret_cast<const float4*>(wp + k0);
        __syncthreads();
        As[lcg + 0][lrow] = av.x;
        As[lcg + 1][lrow] = av.y;
        As[lcg + 2][lrow] = av.z;
        As[lcg + 3][lrow] = av.w;
        Bs[lcg + 0][lrow] = bv.x;
        Bs[lcg + 1][lrow] = bv.y;
        Bs[lcg + 2][lrow] = bv.z;
        Bs[lcg + 3][lrow] = bv.w;
        __syncthreads();
#pragma unroll
        for (int k = 0; k < 16; ++k) {
            float4 a4 = *reinterpret_cast<const float4*>(&As[k][ty * 4]);
            float4 b4 = *reinterpret_cast<const float4*>(&Bs[k][tx * 4]);
            const float* a = reinterpret_cast<const float*>(&a4);
            const float* b = reinterpret_cast<const float*>(&b4);
#pragma unroll
            for (int i = 0; i < 4; ++i)
#pragma unroll
                for (int j = 0; j < 4; ++j) acc[i][j] = fmaf(a[i], b[j], acc[i][j]);
        }
    }
#pragma unroll
    for (int i = 0; i < 4; ++i) {
        const int m = gm0 + ty * 4 + i;
#pragma unroll
        for (int j = 0; j < 4; ++j) {
            const int n = gn0 + tx * 4 + j;
            float val = acc[i][j] + bias[n];
            if (MODE == 1) {
                const int b_ = m >> 11, s_ = m & (NS - 1);
                const int h_ = n >> 6, dk = n & (NDK - 1);
                ((bf16_t*)outp)[(((size_t)(b_ * NH + h_)) * NS + s_) * NDK + dk] =
                    __float2bfloat16(val);
            } else {
                ((float*)outp)[(size_t)m * ND + n] = val;
            }
        }
    }
}

// ---------------------------------------------------------------------------
// Kernel 3: MFMA flash attention (bf16 operands, fp32 accumulate).
// Block = 64 q-rows of one (b,h); 4 warps x 16 q. 32 key-tiles of 64.
// Swapped QK^T: mfma(K,Q) -> S^T  (q = lane&15, key = (lane>>4)*4+reg).
// P staged per-warp in LDS; PV in natural layout via V^T tiles in LDS.
// ---------------------------------------------------------------------------
__global__ __launch_bounds__(256) void flash_mfma(const bf16_t* __restrict__ Qh,
                                                  const bf16_t* __restrict__ Kh,
                                                  const bf16_t* __restrict__ Vh,
                                                  const float* __restrict__ comb,
                                                  float* __restrict__ attnOut,
                                                  float* __restrict__ concatOut) {
    __shared__ __align__(16) unsigned short Kt[64][72];      // [key][dk]
    __shared__ __align__(16) unsigned short Vt[64][72];      // [dk][key]
    __shared__ __align__(16) unsigned short Pt[4][16][72];   // per-warp [q][key]

    const int tid = threadIdx.x;
    const int w = tid >> 6;
    const int lane = tid & 63;
    const int qc = lane & 15;   // column index (q for S^T / O tiles)
    const int g = lane >> 4;    // 0..3
    const int bh = blockIdx.y;
    const int b_ = bh >> 4, h_ = bh & 15;
    const int qw = blockIdx.x * 64 + w * 16;  // warp's q base

    const size_t bhoff = (size_t)bh * NS * NDK;
    const unsigned short* Kg = (const unsigned short*)Kh + bhoff;
    const unsigned short* Vg = (const unsigned short*)Vh + bhoff;

    // Q fragments held in registers for the whole kernel
    bf16x8 qf[2];
    {
        const unsigned short* qp =
            (const unsigned short*)Qh + bhoff + (size_t)(qw + qc) * NDK + g * 8;
        qf[0] = *(const bf16x8*)(qp);
        qf[1] = *(const bf16x8*)(qp + 32);
    }

    f32x4 zero4 = {0.f, 0.f, 0.f, 0.f};
    f32x4 o[4];
    o[0] = o[1] = o[2] = o[3] = zero4;
    float mrun = -1e30f, lsum = 0.f;

    // staging indices
    const int skey = tid >> 2;         // K stage: row
    const int sdk = (tid & 3) * 16;    // K stage: dk group (16 elems)
    const int vkp = tid & 31;          // V stage: key pair
    const int vdk = (tid >> 5) * 8;    // V stage: dk group (8 elems)

    const float* crow = comb + (size_t)(qw + qc) * NS;

    for (int kt = 0; kt < NS; kt += 64) {
        // global -> registers
        int4 ka = *(const int4*)(Kg + (size_t)(kt + skey) * NDK + sdk);
        int4 kb = *(const int4*)(Kg + (size_t)(kt + skey) * NDK + sdk + 8);
        int4 va = *(const int4*)(Vg + (size_t)(kt + 2 * vkp) * NDK + vdk);
        int4 vb = *(const int4*)(Vg + (size_t)(kt + 2 * vkp + 1) * NDK + vdk);
        __syncthreads();
        // registers -> LDS
        *(int4*)&Kt[skey][sdk] = ka;
        *(int4*)&Kt[skey][sdk + 8] = kb;
        {
            const unsigned short* a = (const unsigned short*)&va;
            const unsigned short* b = (const unsigned short*)&vb;
#pragma unroll
            for (int j = 0; j < 8; ++j) {
                unsigned int pk = (unsigned int)a[j] | ((unsigned int)b[j] << 16);
                *(unsigned int*)&Vt[vdk + j][2 * vkp] = pk;
            }
        }
        __syncthreads();

        // ---- QK^T -> S^T [64 key][16 q] ----
        f32x4 s[4];
        s[0] = s[1] = s[2] = s[3] = zero4;
#pragma unroll
        for (int kc = 0; kc < 2; ++kc) {
#pragma unroll
            for (int ks = 0; ks < 4; ++ks) {
                bf16x8 kf = *(const bf16x8*)&Kt[ks * 16 + qc][kc * 32 + g * 8];
                s[ks] = __builtin_amdgcn_mfma_f32_16x16x32_bf16(kf, qf[kc], s[ks], 0, 0, 0);
            }
        }

        // ---- mask + logits ----
        float lg[16];
        float tmax = -1e30f;
#pragma unroll
        for (int ks = 0; ks < 4; ++ks) {
            float4 c4 = *(const float4*)(crow + kt + ks * 16 + g * 4);
            const float* cc = (const float*)&c4;
#pragma unroll
            for (int r = 0; r < 4; ++r) {
                float sv = s[ks][r] * 0.125f;  // 1/sqrt(64)
                float l_ = (cc[r] < 0.f) ? -1e30f : sv * cc[r];
                lg[ks * 4 + r] = l_;
                tmax = fmaxf(tmax, l_);
            }
        }
        tmax = fmaxf(tmax, __shfl_xor(tmax, 16));
        tmax = fmaxf(tmax, __shfl_xor(tmax, 32));
        const float mnew = fmaxf(mrun, tmax);
        const float scl = __expf(mrun - mnew);
        mrun = mnew;
        lsum *= scl;
        // rescale O (rows q = g*4+r need scale from lane g*4+r)
        float sr[4];
#pragma unroll
        for (int r = 0; r < 4; ++r) sr[r] = __shfl(scl, g * 4 + r);
#pragma unroll
        for (int dsub = 0; dsub < 4; ++dsub)
#pragma unroll
            for (int r = 0; r < 4; ++r) o[dsub][r] *= sr[r];

        // ---- p = exp, accumulate lsum, write P (bf16) to per-warp LDS ----
#pragma unroll
        for (int ks = 0; ks < 4; ++ks) {
            float p0 = (lg[ks * 4 + 0] < -1e29f) ? 0.f : __expf(lg[ks * 4 + 0] - mnew);
            float p1 = (lg[ks * 4 + 1] < -1e29f) ? 0.f : __expf(lg[ks * 4 + 1] - mnew);
            float p2 = (lg[ks * 4 + 2] < -1e29f) ? 0.f : __expf(lg[ks * 4 + 2] - mnew);
            float p3 = (lg[ks * 4 + 3] < -1e29f) ? 0.f : __expf(lg[ks * 4 + 3] - mnew);
            lsum += (p0 + p1) + (p2 + p3);
            unsigned int w0 = (unsigned int)f2bf(p0) | ((unsigned int)f2bf(p1) << 16);
            unsigned int w1 = (unsigned int)f2bf(p2) | ((unsigned int)f2bf(p3) << 16);
            *(unsigned int*)&Pt[w][qc][ks * 16 + g * 4] = w0;
            *(unsigned int*)&Pt[w][qc][ks * 16 + g * 4 + 2] = w1;
        }

        // ---- PV: O[q][d] += P[q][key] * V[key][d] ----
#pragma unroll
        for (int kc = 0; kc < 2; ++kc) {
            bf16x8 pf = *(const bf16x8*)&Pt[w][qc][kc * 32 + g * 8];
#pragma unroll
            for (int dsub = 0; dsub < 4; ++dsub) {
                bf16x8 vf = *(const bf16x8*)&Vt[dsub * 16 + qc][kc * 32 + g * 8];
                o[dsub] = __builtin_amdgcn_mfma_f32_16x16x32_bf16(pf, vf, o[dsub], 0, 0, 0);
            }
        }
    }

    // ---- normalize + store (attn [B,H,S,DK] and concat [B,S,D]) ----
    lsum += __shfl_xor(lsum, 16);
    lsum += __shfl_xor(lsum, 32);
    const float linv = 1.0f / lsum;
    float inv[4];
#pragma unroll
    for (int r = 0; r < 4; ++r) inv[r] = __shfl(linv, g * 4 + r);

#pragma unroll
    for (int dsub = 0; dsub < 4; ++dsub) {
#pragma unroll
        for (int r = 0; r < 4; ++r) {
            const float val = o[dsub][r] * inv[r];
            const int qg = qw + g * 4 + r;
            const int d = dsub * 16 + qc;
            attnOut[bhoff + (size_t)qg * NDK + d] = val;
            concatOut[((size_t)b_ * NS + qg) * ND + h_ * NDK + d] = val;
        }
    }
}

// ---------------------------------------------------------------------------
extern "C" void kernel_launch(void* const* d_in, const int* in_sizes, int n_in,
                              void* d_out, int out_size, void* d_ws, size_t ws_size,
                              hipStream_t stream) {
    const float* q = (const float*)d_in[0];
    const float* k = (const float*)d_in[1];
    const float* v = (const float*)d_in[2];
    const int* am = (const int*)d_in[3];
    const float* cm = (const float*)d_in[4];
    const float* Wq = (const float*)d_in[5];
    const float* bq = (const float*)d_in[6];
    const float* Wk = (const float*)d_in[7];
    const float* bk = (const float*)d_in[8];
    const float* Wv = (const float*)d_in[9];
    const float* bv = (const float*)d_in[10];
    const float* Wo = (const float*)d_in[11];
    const float* bo = (const float*)d_in[12];

    float* out = (float*)d_out;                    // [B,S,D]
    float* attn_out = out + (size_t)NB * NS * ND;  // [B,H,S,DK]

    float* ws = (float*)d_ws;
    float* CC = ws;                 // concat [B,S,D] fp32: 4194304 floats
    float* CB = ws + 4194304;       // combined mask [S,S] fp32: 4194304 floats
    bf16_t* Qb = (bf16_t*)(ws + 8388608);  // [B,H,S,DK] bf16
    bf16_t* Kb = Qb + 4194304;
    bf16_t* Vb = Kb + 4194304;

    hipLaunchKernelGGL(mask_combine_kernel, dim3(4096), dim3(256), 0, stream, am, cm, CB);
    hipLaunchKernelGGL((proj_kernel<1>), dim3(16, 64), dim3(256), 0, stream, q, Wq, bq,
                       (void*)Qb);
    hipLaunchKernelGGL((proj_kernel<1>), dim3(16, 64), dim3(256), 0, stream, k, Wk, bk,
                       (void*)Kb);
    hipLaunchKernelGGL((proj_kernel<1>), dim3(16, 64), dim3(256), 0, stream, v, Wv, bv,
                       (void*)Vb);
    hipLaunchKernelGGL(flash_mfma, dim3(NS / 64, NB * NH), dim3(256), 0, stream, Qb, Kb, Vb,
                       CB, attn_out, CC);
    hipLaunchKernelGGL((proj_kernel<0>), dim3(16, 64), dim3(256), 0, stream, CC, Wo, bo,
                       (void*)out);
}

// Round 3
// 375.699 us; speedup vs baseline: 8.2848x; 1.6121x over previous
//
#include <hip/hip_runtime.h>
#include <hip/hip_bf16.h>

#define NB 2
#define NS 2048
#define ND 1024
#define NH 16
#define NDK 64
#define GK 1024  // GEMM K (= ND)

using bf16_t = __hip_bfloat16;
typedef __attribute__((ext_vector_type(8))) short bf16x8;
typedef __attribute__((ext_vector_type(4))) float f32x4;

static __device__ __forceinline__ unsigned short f2bf(float f) {
    __hip_bfloat16 h = __float2bfloat16(f);
    return *reinterpret_cast<unsigned short*>(&h);
}

// ---------------------------------------------------------------------------
// Kernel 0: fp32 -> bf16 elementwise convert (vectorized 4-wide)
// ---------------------------------------------------------------------------
__global__ void f2b_kernel(const float* __restrict__ src, unsigned short* __restrict__ dst,
                           int n4) {
    int i = blockIdx.x * 256 + threadIdx.x;
    if (i < n4) {
        float4 v = reinterpret_cast<const float4*>(src)[i];
        ushort4 o;
        o.x = f2bf(v.x);
        o.y = f2bf(v.y);
        o.z = f2bf(v.z);
        o.w = f2bf(v.w);
        reinterpret_cast<ushort4*>(dst)[i] = o;
    }
}

// ---------------------------------------------------------------------------
// Kernel 1: combined mask  comb = (attn_mask==1) ? -1 : (1 + 0.5*causal)
// ---------------------------------------------------------------------------
__global__ void mask_combine_kernel(const int* __restrict__ am,
                                    const float* __restrict__ cm,
                                    float* __restrict__ outc) {
    int i = (blockIdx.x * 256 + threadIdx.x) * 4;
    int4 a = *reinterpret_cast<const int4*>(am + i);
    float4 c = *reinterpret_cast<const float4*>(cm + i);
    float4 r;
    r.x = (a.x == 1) ? -1.0f : fmaf(0.5f, c.x, 1.0f);
    r.y = (a.y == 1) ? -1.0f : fmaf(0.5f, c.y, 1.0f);
    r.z = (a.z == 1) ? -1.0f : fmaf(0.5f, c.z, 1.0f);
    r.w = (a.w == 1) ? -1.0f : fmaf(0.5f, c.w, 1.0f);
    *reinterpret_cast<float4*>(outc + i) = r;
}

// ---------------------------------------------------------------------------
// Kernel 2: bf16 MFMA GEMM  C[m][n] = sum_k A[m][k]*B[n][k] + bias[n]
// A [4096][1024], B [1024][1024], both bf16 K-contiguous.
// BM=128 BN=64 BK=64, 256 thr / 4 waves (2x2), wave = 4x2 frags 16x16x32.
// LDS rows padded to 72 bf16 (144B): 16B-aligned, conflict-free frag reads.
// MODE 0: fp32 out [4096][1024].  MODE 1: bf16 out in [B,H,S,DK] layout.
// ---------------------------------------------------------------------------
template <int MODE>
__global__ __launch_bounds__(256) void mm_bf16(const unsigned short* __restrict__ A,
                                               const unsigned short* __restrict__ Bm,
                                               const float* __restrict__ bias,
                                               void* __restrict__ outp) {
    __shared__ __align__(16) unsigned short As[128][72];
    __shared__ __align__(16) unsigned short Bs[64][72];
    const int tid = threadIdx.x;
    const int lane = tid & 63;
    const int w = tid >> 6;
    const int wm = w >> 1, wn = w & 1;
    const int bm0 = blockIdx.y * 128, bn0 = blockIdx.x * 64;

    // staging: A 128x64 bf16 (16KB) -> 4 x int4 per thread; B 64x64 -> 2 x int4
    const int ar = tid >> 1;
    const int ah = (tid & 1) * 32;
    const int br = tid >> 2;
    const int bq = (tid & 3) * 16;
    const unsigned short* Ap = A + (size_t)(bm0 + ar) * GK + ah;
    const unsigned short* Bp = Bm + (size_t)(bn0 + br) * GK + bq;

    int4 areg[4], breg[2];
#pragma unroll
    for (int i = 0; i < 4; ++i) areg[i] = *(const int4*)(Ap + i * 8);
#pragma unroll
    for (int i = 0; i < 2; ++i) breg[i] = *(const int4*)(Bp + i * 8);

    f32x4 acc[4][2];
    const f32x4 z4 = {0.f, 0.f, 0.f, 0.f};
#pragma unroll
    for (int i = 0; i < 4; ++i)
#pragma unroll
        for (int j = 0; j < 2; ++j) acc[i][j] = z4;

    const int fr = lane & 15;   // fragment row/col index
    const int fg = lane >> 4;   // k-group 0..3

    for (int kt = 0; kt < GK / 64; ++kt) {
        __syncthreads();
#pragma unroll
        for (int i = 0; i < 4; ++i) *(int4*)&As[ar][ah + i * 8] = areg[i];
#pragma unroll
        for (int i = 0; i < 2; ++i) *(int4*)&Bs[br][bq + i * 8] = breg[i];
        __syncthreads();
        if (kt + 1 < GK / 64) {
            const int ko = (kt + 1) * 64;
#pragma unroll
            for (int i = 0; i < 4; ++i) areg[i] = *(const int4*)(Ap + ko + i * 8);
#pragma unroll
            for (int i = 0; i < 2; ++i) breg[i] = *(const int4*)(Bp + ko + i * 8);
        }
#pragma unroll
        for (int s = 0; s < 2; ++s) {
            bf16x8 af[4], bfr[2];
#pragma unroll
            for (int i = 0; i < 4; ++i)
                af[i] = *(const bf16x8*)&As[wm * 64 + i * 16 + fr][s * 32 + fg * 8];
#pragma unroll
            for (int j = 0; j < 2; ++j)
                bfr[j] = *(const bf16x8*)&Bs[wn * 32 + j * 16 + fr][s * 32 + fg * 8];
#pragma unroll
            for (int i = 0; i < 4; ++i)
#pragma unroll
                for (int j = 0; j < 2; ++j)
                    acc[i][j] =
                        __builtin_amdgcn_mfma_f32_16x16x32_bf16(af[i], bfr[j], acc[i][j], 0, 0, 0);
        }
    }

#pragma unroll
    for (int j = 0; j < 2; ++j) {
        const int col = bn0 + wn * 32 + j * 16 + fr;
        const float bv_ = bias[col];
#pragma unroll
        for (int i = 0; i < 4; ++i) {
#pragma unroll
            for (int r = 0; r < 4; ++r) {
                const int row = bm0 + wm * 64 + i * 16 + fg * 4 + r;
                const float val = acc[i][j][r] + bv_;
                if (MODE == 1) {
                    const int b_ = row >> 11, s_ = row & (NS - 1);
                    const int h_ = col >> 6, dk = col & (NDK - 1);
                    ((bf16_t*)outp)[(((size_t)(b_ * NH + h_)) * NS + s_) * NDK + dk] =
                        __float2bfloat16(val);
                } else {
                    ((float*)outp)[(size_t)row * ND + col] = val;
                }
            }
        }
    }
}

// ---------------------------------------------------------------------------
// Kernel 3: MFMA flash attention (bf16 operands, fp32 accumulate).
// Block = 64 q-rows of one (b,h); 4 warps x 16 q. 32 key-tiles of 64.
// Swapped QK^T: mfma(K,Q) -> S^T (q = lane&15, key = (lane>>4)*4+reg).
// Writes attn fp32 [B,H,S,DK] and concat bf16 [B,S,D].
// ---------------------------------------------------------------------------
__global__ __launch_bounds__(256) void flash_mfma(const bf16_t* __restrict__ Qh,
                                                  const bf16_t* __restrict__ Kh,
                                                  const bf16_t* __restrict__ Vh,
                                                  const float* __restrict__ comb,
                                                  float* __restrict__ attnOut,
                                                  unsigned short* __restrict__ concatOut) {
    __shared__ __align__(16) unsigned short Kt[64][72];      // [key][dk]
    __shared__ __align__(16) unsigned short Vt[64][72];      // [dk][key]
    __shared__ __align__(16) unsigned short Pt[4][16][72];   // per-warp [q][key]

    const int tid = threadIdx.x;
    const int w = tid >> 6;
    const int lane = tid & 63;
    const int qc = lane & 15;
    const int g = lane >> 4;
    const int bh = blockIdx.y;
    const int b_ = bh >> 4, h_ = bh & 15;
    const int qw = blockIdx.x * 64 + w * 16;

    const size_t bhoff = (size_t)bh * NS * NDK;
    const unsigned short* Kg = (const unsigned short*)Kh + bhoff;
    const unsigned short* Vg = (const unsigned short*)Vh + bhoff;

    bf16x8 qf[2];
    {
        const unsigned short* qp =
            (const unsigned short*)Qh + bhoff + (size_t)(qw + qc) * NDK + g * 8;
        qf[0] = *(const bf16x8*)(qp);
        qf[1] = *(const bf16x8*)(qp + 32);
    }

    f32x4 zero4 = {0.f, 0.f, 0.f, 0.f};
    f32x4 o[4];
    o[0] = o[1] = o[2] = o[3] = zero4;
    float mrun = -1e30f, lsum = 0.f;

    const int skey = tid >> 2;
    const int sdk = (tid & 3) * 16;
    const int vkp = tid & 31;
    const int vdk = (tid >> 5) * 8;

    const float* crow = comb + (size_t)(qw + qc) * NS;

    for (int kt = 0; kt < NS; kt += 64) {
        int4 ka = *(const int4*)(Kg + (size_t)(kt + skey) * NDK + sdk);
        int4 kb = *(const int4*)(Kg + (size_t)(kt + skey) * NDK + sdk + 8);
        int4 va = *(const int4*)(Vg + (size_t)(kt + 2 * vkp) * NDK + vdk);
        int4 vb = *(const int4*)(Vg + (size_t)(kt + 2 * vkp + 1) * NDK + vdk);
        __syncthreads();
        *(int4*)&Kt[skey][sdk] = ka;
        *(int4*)&Kt[skey][sdk + 8] = kb;
        {
            const unsigned short* a = (const unsigned short*)&va;
            const unsigned short* b = (const unsigned short*)&vb;
#pragma unroll
            for (int j = 0; j < 8; ++j) {
                unsigned int pk = (unsigned int)a[j] | ((unsigned int)b[j] << 16);
                *(unsigned int*)&Vt[vdk + j][2 * vkp] = pk;
            }
        }
        __syncthreads();

        f32x4 s[4];
        s[0] = s[1] = s[2] = s[3] = zero4;
#pragma unroll
        for (int kc = 0; kc < 2; ++kc) {
#pragma unroll
            for (int ks = 0; ks < 4; ++ks) {
                bf16x8 kf = *(const bf16x8*)&Kt[ks * 16 + qc][kc * 32 + g * 8];
                s[ks] = __builtin_amdgcn_mfma_f32_16x16x32_bf16(kf, qf[kc], s[ks], 0, 0, 0);
            }
        }

        float lg[16];
        float tmax = -1e30f;
#pragma unroll
        for (int ks = 0; ks < 4; ++ks) {
            float4 c4 = *(const float4*)(crow + kt + ks * 16 + g * 4);
            const float* cc = (const float*)&c4;
#pragma unroll
            for (int r = 0; r < 4; ++r) {
                float sv = s[ks][r] * 0.125f;
                float l_ = (cc[r] < 0.f) ? -1e30f : sv * cc[r];
                lg[ks * 4 + r] = l_;
                tmax = fmaxf(tmax, l_);
            }
        }
        tmax = fmaxf(tmax, __shfl_xor(tmax, 16));
        tmax = fmaxf(tmax, __shfl_xor(tmax, 32));
        const float mnew = fmaxf(mrun, tmax);
        const float scl = __expf(mrun - mnew);
        mrun = mnew;
        lsum *= scl;
        float sr[4];
#pragma unroll
        for (int r = 0; r < 4; ++r) sr[r] = __shfl(scl, g * 4 + r);
#pragma unroll
        for (int dsub = 0; dsub < 4; ++dsub)
#pragma unroll
            for (int r = 0; r < 4; ++r) o[dsub][r] *= sr[r];

#pragma unroll
        for (int ks = 0; ks < 4; ++ks) {
            float p0 = (lg[ks * 4 + 0] < -1e29f) ? 0.f : __expf(lg[ks * 4 + 0] - mnew);
            float p1 = (lg[ks * 4 + 1] < -1e29f) ? 0.f : __expf(lg[ks * 4 + 1] - mnew);
            float p2 = (lg[ks * 4 + 2] < -1e29f) ? 0.f : __expf(lg[ks * 4 + 2] - mnew);
            float p3 = (lg[ks * 4 + 3] < -1e29f) ? 0.f : __expf(lg[ks * 4 + 3] - mnew);
            lsum += (p0 + p1) + (p2 + p3);
            unsigned int w0 = (unsigned int)f2bf(p0) | ((unsigned int)f2bf(p1) << 16);
            unsigned int w1 = (unsigned int)f2bf(p2) | ((unsigned int)f2bf(p3) << 16);
            *(unsigned int*)&Pt[w][qc][ks * 16 + g * 4] = w0;
            *(unsigned int*)&Pt[w][qc][ks * 16 + g * 4 + 2] = w1;
        }

#pragma unroll
        for (int kc = 0; kc < 2; ++kc) {
            bf16x8 pf = *(const bf16x8*)&Pt[w][qc][kc * 32 + g * 8];
#pragma unroll
            for (int dsub = 0; dsub < 4; ++dsub) {
                bf16x8 vf = *(const bf16x8*)&Vt[dsub * 16 + qc][kc * 32 + g * 8];
                o[dsub] = __builtin_amdgcn_mfma_f32_16x16x32_bf16(pf, vf, o[dsub], 0, 0, 0);
            }
        }
    }

    lsum += __shfl_xor(lsum, 16);
    lsum += __shfl_xor(lsum, 32);
    const float linv = 1.0f / lsum;
    float inv[4];
#pragma unroll
    for (int r = 0; r < 4; ++r) inv[r] = __shfl(linv, g * 4 + r);

#pragma unroll
    for (int dsub = 0; dsub < 4; ++dsub) {
#pragma unroll
        for (int r = 0; r < 4; ++r) {
            const float val = o[dsub][r] * inv[r];
            const int qg = qw + g * 4 + r;
            const int d = dsub * 16 + qc;
            attnOut[bhoff + (size_t)qg * NDK + d] = val;
            concatOut[((size_t)b_ * NS + qg) * ND + h_ * NDK + d] = f2bf(val);
        }
    }
}

// ---------------------------------------------------------------------------
extern "C" void kernel_launch(void* const* d_in, const int* in_sizes, int n_in,
                              void* d_out, int out_size, void* d_ws, size_t ws_size,
                              hipStream_t stream) {
    const float* q = (const float*)d_in[0];
    const float* k = (const float*)d_in[1];
    const float* v = (const float*)d_in[2];
    const int* am = (const int*)d_in[3];
    const float* cm = (const float*)d_in[4];
    const float* Wq = (const float*)d_in[5];
    const float* bq = (const float*)d_in[6];
    const float* Wk = (const float*)d_in[7];
    const float* bk = (const float*)d_in[8];
    const float* Wv = (const float*)d_in[9];
    const float* bv = (const float*)d_in[10];
    const float* Wo = (const float*)d_in[11];
    const float* bo = (const float*)d_in[12];

    float* out = (float*)d_out;                    // [B,S,D] fp32
    float* attn_out = out + (size_t)NB * NS * ND;  // [B,H,S,DK] fp32

    char* p = (char*)d_ws;
    float* CB = (float*)p;                 p += (size_t)NS * NS * 4;         // 16 MB
    unsigned short* qb = (unsigned short*)p;  p += (size_t)NB * NS * ND * 2; // 8 MB
    unsigned short* kb_ = (unsigned short*)p; p += (size_t)NB * NS * ND * 2;
    unsigned short* vb_ = (unsigned short*)p; p += (size_t)NB * NS * ND * 2;
    unsigned short* Wqb = (unsigned short*)p; p += (size_t)ND * ND * 2;      // 2 MB
    unsigned short* Wkb = (unsigned short*)p; p += (size_t)ND * ND * 2;
    unsigned short* Wvb = (unsigned short*)p; p += (size_t)ND * ND * 2;
    unsigned short* Wob = (unsigned short*)p; p += (size_t)ND * ND * 2;
    unsigned short* Qh = (unsigned short*)p;  p += (size_t)NB * NS * ND * 2; // 8 MB
    unsigned short* Kh = (unsigned short*)p;  p += (size_t)NB * NS * ND * 2;
    unsigned short* Vh = (unsigned short*)p;  p += (size_t)NB * NS * ND * 2;
    unsigned short* CCb = (unsigned short*)p; p += (size_t)NB * NS * ND * 2;

    const int n4_in = NB * NS * ND / 4;  // 1048576
    const int n4_w = ND * ND / 4;        // 262144

    hipLaunchKernelGGL(mask_combine_kernel, dim3(4096), dim3(256), 0, stream, am, cm, CB);
    hipLaunchKernelGGL(f2b_kernel, dim3(n4_in / 256), dim3(256), 0, stream, q, qb, n4_in);
    hipLaunchKernelGGL(f2b_kernel, dim3(n4_in / 256), dim3(256), 0, stream, k, kb_, n4_in);
    hipLaunchKernelGGL(f2b_kernel, dim3(n4_in / 256), dim3(256), 0, stream, v, vb_, n4_in);
    hipLaunchKernelGGL(f2b_kernel, dim3(n4_w / 256), dim3(256), 0, stream, Wq, Wqb, n4_w);
    hipLaunchKernelGGL(f2b_kernel, dim3(n4_w / 256), dim3(256), 0, stream, Wk, Wkb, n4_w);
    hipLaunchKernelGGL(f2b_kernel, dim3(n4_w / 256), dim3(256), 0, stream, Wv, Wvb, n4_w);
    hipLaunchKernelGGL(f2b_kernel, dim3(n4_w / 256), dim3(256), 0, stream, Wo, Wob, n4_w);

    hipLaunchKernelGGL((mm_bf16<1>), dim3(16, 32), dim3(256), 0, stream, qb, Wqb, bq, (void*)Qh);
    hipLaunchKernelGGL((mm_bf16<1>), dim3(16, 32), dim3(256), 0, stream, kb_, Wkb, bk, (void*)Kh);
    hipLaunchKernelGGL((mm_bf16<1>), dim3(16, 32), dim3(256), 0, stream, vb_, Wvb, bv, (void*)Vh);

    hipLaunchKernelGGL(flash_mfma, dim3(NS / 64, NB * NH), dim3(256), 0, stream,
                       (const bf16_t*)Qh, (const bf16_t*)Kh, (const bf16_t*)Vh, CB, attn_out,
                       CCb);

    hipLaunchKernelGGL((mm_bf16<0>), dim3(16, 32), dim3(256), 0, stream, CCb, Wob, bo,
                       (void*)out);
}

// Round 4
// 207.560 us; speedup vs baseline: 14.9961x; 1.8101x over previous
//
#include <hip/hip_runtime.h>
#include <hip/hip_bf16.h>

#define NB 2
#define NS 2048
#define ND 1024
#define NH 16
#define NDK 64
#define GK 1024  // GEMM K (= ND)

using bf16_t = __hip_bfloat16;
typedef __attribute__((ext_vector_type(8))) short bf16x8;
typedef __attribute__((ext_vector_type(4))) float f32x4;
typedef unsigned short u16;

static __device__ __forceinline__ u16 f2bf(float f) {
    __hip_bfloat16 h = __float2bfloat16(f);
    return *reinterpret_cast<u16*>(&h);
}

// async global->LDS DMA, 16B per lane. lp MUST be wave-uniform; gp is per-lane.
#define GLDS16(gp, lp)                                                                   \
    __builtin_amdgcn_global_load_lds((const __attribute__((address_space(1))) void*)(gp), \
                                     (__attribute__((address_space(3))) void*)(lp), 16, 0, 0)

// ---------------------------------------------------------------------------
// Kernel 0: fused fp32 -> bf16 converts (grid.y selects tensor)
// ---------------------------------------------------------------------------
struct CvtArgs {
    const float* s[4];
    u16* d[4];
};

__global__ void f2b_multi(CvtArgs a) {
    const float* s = a.s[blockIdx.y];
    u16* d = a.d[blockIdx.y];
    int i = blockIdx.x * 256 + threadIdx.x;
    float4 v = reinterpret_cast<const float4*>(s)[i];
    ushort4 o;
    o.x = f2bf(v.x);
    o.y = f2bf(v.y);
    o.z = f2bf(v.z);
    o.w = f2bf(v.w);
    reinterpret_cast<ushort4*>(d)[i] = o;
}

// ---------------------------------------------------------------------------
// Kernel 1: combined mask  comb = (attn_mask==1) ? -1 : (1 + 0.5*causal)
// ---------------------------------------------------------------------------
__global__ void mask_combine_kernel(const int* __restrict__ am,
                                    const float* __restrict__ cm,
                                    float* __restrict__ outc) {
    int i = (blockIdx.x * 256 + threadIdx.x) * 4;
    int4 a = *reinterpret_cast<const int4*>(am + i);
    float4 c = *reinterpret_cast<const float4*>(cm + i);
    float4 r;
    r.x = (a.x == 1) ? -1.0f : fmaf(0.5f, c.x, 1.0f);
    r.y = (a.y == 1) ? -1.0f : fmaf(0.5f, c.y, 1.0f);
    r.z = (a.z == 1) ? -1.0f : fmaf(0.5f, c.z, 1.0f);
    r.w = (a.w == 1) ? -1.0f : fmaf(0.5f, c.w, 1.0f);
    *reinterpret_cast<float4*>(outc + i) = r;
}

// ---------------------------------------------------------------------------
// Kernel 2: m97-style bf16 MFMA GEMM with global_load_lds staging.
// C[m][n] = sum_k A[m][k]*B[n][k] + bias[n].  BM=128, BK=32, dbuf LDS.
// BN=128: 4 waves 2x2, wave 64x64, 16 MFMA : 8 ds_read per K-step.
// BN=64 : 4 waves 2x2, wave 64x32.
// MODE 0: fp32 [M][ND] out.  MODE 1: bf16 out in [B,H,S,DK] layout.
// blockIdx.z selects one of 3 argument sets (QKV fused launch).
// ---------------------------------------------------------------------------
struct MMArgs {
    const u16* A;
    const u16* W;
    const float* bias;
    void* out;
};

template <int BN, int MODE>
__global__ __launch_bounds__(256) void mm_glds(MMArgs g0, MMArgs g1, MMArgs g2) {
    const MMArgs ga = (blockIdx.z == 0) ? g0 : (blockIdx.z == 1) ? g1 : g2;
    constexpr int BM = 128, BK = 32;
    constexpr int JN = BN / 32;  // col-frags per wave (4 or 2)
    __shared__ __align__(16) u16 As[2][BM * BK];
    __shared__ __align__(16) u16 Bs[2][BN * BK];

    const int tid = threadIdx.x;
    const int lane = tid & 63;
    const int w = tid >> 6;
    const int wm = w >> 1, wn = w & 1;
    const int fr = lane & 15, fg = lane >> 4;
    const int bm0 = blockIdx.y * BM, bn0 = blockIdx.x * BN;

    // staging addresses: chunk = 16 rows x 32 bf16 (1KB = 64 lanes x 16B)
    // lane -> row chunk*16 + (lane>>2), col bf16 (lane&3)*8
    const u16* agp = ga.A + (size_t)(bm0 + w * 32 + (lane >> 2)) * GK + (lane & 3) * 8;
    const u16* bgp = ga.W +
                     (size_t)(bn0 + w * (BN == 128 ? 32 : 16) + (lane >> 2)) * GK +
                     (lane & 3) * 8;

    f32x4 acc[4][JN];
    const f32x4 z4 = {0.f, 0.f, 0.f, 0.f};
#pragma unroll
    for (int i = 0; i < 4; ++i)
#pragma unroll
        for (int j = 0; j < JN; ++j) acc[i][j] = z4;

    // prologue stage of tile 0 into buf 0
    {
        u16* la = &As[0][w * 1024];
        u16* lb = &Bs[0][w * (BN == 128 ? 1024 : 512)];
        GLDS16(agp, la);
        GLDS16(agp + 16 * GK, la + 512);
        if (BN == 128) {
            GLDS16(bgp, lb);
            GLDS16(bgp + 16 * GK, lb + 512);
        } else {
            GLDS16(bgp, lb);
        }
    }
    __syncthreads();

    int cur = 0;
    for (int kt = 0; kt < GK / BK; ++kt) {
        // issue next tile's loads into the other buffer (overlaps with MFMA below)
        if (kt + 1 < GK / BK) {
            const int ko = (kt + 1) * BK;
            u16* la = &As[cur ^ 1][w * 1024];
            u16* lb = &Bs[cur ^ 1][w * (BN == 128 ? 1024 : 512)];
            GLDS16(agp + ko, la);
            GLDS16(agp + ko + 16 * GK, la + 512);
            if (BN == 128) {
                GLDS16(bgp + ko, lb);
                GLDS16(bgp + ko + 16 * GK, lb + 512);
            } else {
                GLDS16(bgp + ko, lb);
            }
        }
        // compute on current buffer
        bf16x8 af[4], bfr[JN];
#pragma unroll
        for (int i = 0; i < 4; ++i)
            af[i] = *(const bf16x8*)&As[cur][(wm * 64 + i * 16 + fr) * BK + fg * 8];
#pragma unroll
        for (int j = 0; j < JN; ++j)
            bfr[j] = *(const bf16x8*)&Bs[cur][(wn * (BN / 2) + j * 16 + fr) * BK + fg * 8];
#pragma unroll
        for (int i = 0; i < 4; ++i)
#pragma unroll
            for (int j = 0; j < JN; ++j)
                acc[i][j] = __builtin_amdgcn_mfma_f32_16x16x32_bf16(af[i], bfr[j], acc[i][j],
                                                                    0, 0, 0);
        __syncthreads();  // drains DMA (vmcnt0) + protects buffer swap
        cur ^= 1;
    }

#pragma unroll
    for (int j = 0; j < JN; ++j) {
        const int col = bn0 + wn * (BN / 2) + j * 16 + fr;
        const float bv_ = ga.bias[col];
#pragma unroll
        for (int i = 0; i < 4; ++i) {
#pragma unroll
            for (int r = 0; r < 4; ++r) {
                const int row = bm0 + wm * 64 + i * 16 + fg * 4 + r;
                const float val = acc[i][j][r] + bv_;
                if (MODE == 1) {
                    const int b_ = row >> 11, s_ = row & (NS - 1);
                    const int h_ = col >> 6, dk = col & (NDK - 1);
                    ((bf16_t*)ga.out)[(((size_t)(b_ * NH + h_)) * NS + s_) * NDK + dk] =
                        __float2bfloat16(val);
                } else {
                    ((float*)ga.out)[(size_t)row * ND + col] = val;
                }
            }
        }
    }
}

// ---------------------------------------------------------------------------
// Kernel 3: MFMA flash attention (bf16 operands, fp32 accumulate, exp2 domain).
// Block = 64 q-rows of one (b,h); 4 warps x 16 q. 32 key-tiles of 64.
// Swapped QK^T: mfma(K,Q) -> S^T (q = lane&15, key = (lane>>4)*4+reg).
// XCD-aware block swizzle: each XCD owns 4 consecutive bh (K/V fit its L2).
// ---------------------------------------------------------------------------
#define SC_LOG2E 0.1803368801f  // 0.125 * log2(e)

__global__ __launch_bounds__(256) void flash_mfma(const bf16_t* __restrict__ Qh,
                                                  const bf16_t* __restrict__ Kh,
                                                  const bf16_t* __restrict__ Vh,
                                                  const float* __restrict__ comb,
                                                  float* __restrict__ attnOut,
                                                  u16* __restrict__ concatOut) {
    __shared__ __align__(16) u16 Kt[64][72];     // [key][dk]
    __shared__ __align__(16) u16 Vt[64][72];     // [dk][key]
    __shared__ __align__(16) u16 Pt[4][16][72];  // per-warp [q][key]

    const int tid = threadIdx.x;
    const int w = tid >> 6;
    const int lane = tid & 63;
    const int qc = lane & 15;
    const int g = lane >> 4;

    // XCD swizzle: flat (x-fastest) -> virt so each XCD gets contiguous chunk
    const int flat = blockIdx.y * gridDim.x + blockIdx.x;  // 0..1023
    const int virt = (flat & 7) * 128 + (flat >> 3);
    const int bh = virt >> 5;
    const int qb = virt & 31;

    const int b_ = bh >> 4, h_ = bh & 15;
    const int qw = qb * 64 + w * 16;

    const size_t bhoff = (size_t)bh * NS * NDK;
    const u16* Kg = (const u16*)Kh + bhoff;
    const u16* Vg = (const u16*)Vh + bhoff;

    bf16x8 qf[2];
    {
        const u16* qp = (const u16*)Qh + bhoff + (size_t)(qw + qc) * NDK + g * 8;
        qf[0] = *(const bf16x8*)(qp);
        qf[1] = *(const bf16x8*)(qp + 32);
    }

    f32x4 zero4 = {0.f, 0.f, 0.f, 0.f};
    f32x4 o[4];
    o[0] = o[1] = o[2] = o[3] = zero4;
    float mrun = -1e30f, lsum = 0.f;  // log2-domain running max

    const int skey = tid >> 2;
    const int sdk = (tid & 3) * 16;
    const int vkp = tid & 31;
    const int vdk = (tid >> 5) * 8;

    const float* crow = comb + (size_t)(qw + qc) * NS;

    for (int kt = 0; kt < NS; kt += 64) {
        int4 ka = *(const int4*)(Kg + (size_t)(kt + skey) * NDK + sdk);
        int4 kb = *(const int4*)(Kg + (size_t)(kt + skey) * NDK + sdk + 8);
        int4 va = *(const int4*)(Vg + (size_t)(kt + 2 * vkp) * NDK + vdk);
        int4 vb = *(const int4*)(Vg + (size_t)(kt + 2 * vkp + 1) * NDK + vdk);
        __syncthreads();
        *(int4*)&Kt[skey][sdk] = ka;
        *(int4*)&Kt[skey][sdk + 8] = kb;
        {
            const u16* a = (const u16*)&va;
            const u16* b = (const u16*)&vb;
#pragma unroll
            for (int j = 0; j < 8; ++j) {
                unsigned int pk = (unsigned int)a[j] | ((unsigned int)b[j] << 16);
                *(unsigned int*)&Vt[vdk + j][2 * vkp] = pk;
            }
        }
        __syncthreads();

        f32x4 s[4];
        s[0] = s[1] = s[2] = s[3] = zero4;
#pragma unroll
        for (int kc = 0; kc < 2; ++kc) {
#pragma unroll
            for (int ks = 0; ks < 4; ++ks) {
                bf16x8 kf = *(const bf16x8*)&Kt[ks * 16 + qc][kc * 32 + g * 8];
                s[ks] = __builtin_amdgcn_mfma_f32_16x16x32_bf16(kf, qf[kc], s[ks], 0, 0, 0);
            }
        }

        // ---- logits in log2 domain + mask ----
        float lg[16];
        float tmax = -1e30f;
#pragma unroll
        for (int ks = 0; ks < 4; ++ks) {
            float4 c4 = *(const float4*)(crow + kt + ks * 16 + g * 4);
            const float* cc = (const float*)&c4;
#pragma unroll
            for (int r = 0; r < 4; ++r) {
                float sv = s[ks][r] * SC_LOG2E;
                float l_ = (cc[r] < 0.f) ? -1e30f : sv * cc[r];
                lg[ks * 4 + r] = l_;
                tmax = fmaxf(tmax, l_);
            }
        }
        tmax = fmaxf(tmax, __shfl_xor(tmax, 16));
        tmax = fmaxf(tmax, __shfl_xor(tmax, 32));
        const float mnew = fmaxf(mrun, tmax);
        const float scl = exp2f(mrun - mnew);
        mrun = mnew;
        lsum *= scl;
        float sr[4];
#pragma unroll
        for (int r = 0; r < 4; ++r) sr[r] = __shfl(scl, g * 4 + r);
#pragma unroll
        for (int dsub = 0; dsub < 4; ++dsub)
#pragma unroll
            for (int r = 0; r < 4; ++r) o[dsub][r] *= sr[r];

        // ---- p = exp2(lg - mnew)  (masked entries underflow to exactly 0) ----
#pragma unroll
        for (int ks = 0; ks < 4; ++ks) {
            float p0 = exp2f(lg[ks * 4 + 0] - mnew);
            float p1 = exp2f(lg[ks * 4 + 1] - mnew);
            float p2 = exp2f(lg[ks * 4 + 2] - mnew);
            float p3 = exp2f(lg[ks * 4 + 3] - mnew);
            lsum += (p0 + p1) + (p2 + p3);
            uint2 pw;
            pw.x = (unsigned int)f2bf(p0) | ((unsigned int)f2bf(p1) << 16);
            pw.y = (unsigned int)f2bf(p2) | ((unsigned int)f2bf(p3) << 16);
            *(uint2*)&Pt[w][qc][ks * 16 + g * 4] = pw;
        }

#pragma unroll
        for (int kc = 0; kc < 2; ++kc) {
            bf16x8 pf = *(const bf16x8*)&Pt[w][qc][kc * 32 + g * 8];
#pragma unroll
            for (int dsub = 0; dsub < 4; ++dsub) {
                bf16x8 vf = *(const bf16x8*)&Vt[dsub * 16 + qc][kc * 32 + g * 8];
                o[dsub] = __builtin_amdgcn_mfma_f32_16x16x32_bf16(pf, vf, o[dsub], 0, 0, 0);
            }
        }
    }

    lsum += __shfl_xor(lsum, 16);
    lsum += __shfl_xor(lsum, 32);
    const float linv = 1.0f / lsum;
    float inv[4];
#pragma unroll
    for (int r = 0; r < 4; ++r) inv[r] = __shfl(linv, g * 4 + r);

#pragma unroll
    for (int dsub = 0; dsub < 4; ++dsub) {
#pragma unroll
        for (int r = 0; r < 4; ++r) {
            const float val = o[dsub][r] * inv[r];
            const int qg = qw + g * 4 + r;
            const int d = dsub * 16 + qc;
            attnOut[bhoff + (size_t)qg * NDK + d] = val;
            concatOut[((size_t)b_ * NS + qg) * ND + h_ * NDK + d] = f2bf(val);
        }
    }
}

// ---------------------------------------------------------------------------
extern "C" void kernel_launch(void* const* d_in, const int* in_sizes, int n_in,
                              void* d_out, int out_size, void* d_ws, size_t ws_size,
                              hipStream_t stream) {
    const float* q = (const float*)d_in[0];
    const float* k = (const float*)d_in[1];
    const float* v = (const float*)d_in[2];
    const int* am = (const int*)d_in[3];
    const float* cm = (const float*)d_in[4];
    const float* Wq = (const float*)d_in[5];
    const float* bq = (const float*)d_in[6];
    const float* Wk = (const float*)d_in[7];
    const float* bk = (const float*)d_in[8];
    const float* Wv = (const float*)d_in[9];
    const float* bv = (const float*)d_in[10];
    const float* Wo = (const float*)d_in[11];
    const float* bo = (const float*)d_in[12];

    float* out = (float*)d_out;                    // [B,S,D] fp32
    float* attn_out = out + (size_t)NB * NS * ND;  // [B,H,S,DK] fp32

    char* p = (char*)d_ws;
    float* CB = (float*)p;        p += (size_t)NS * NS * 4;
    u16* qb = (u16*)p;            p += (size_t)NB * NS * ND * 2;
    u16* kb_ = (u16*)p;           p += (size_t)NB * NS * ND * 2;
    u16* vb_ = (u16*)p;           p += (size_t)NB * NS * ND * 2;
    u16* Wqb = (u16*)p;           p += (size_t)ND * ND * 2;
    u16* Wkb = (u16*)p;           p += (size_t)ND * ND * 2;
    u16* Wvb = (u16*)p;           p += (size_t)ND * ND * 2;
    u16* Wob = (u16*)p;           p += (size_t)ND * ND * 2;
    u16* Qh = (u16*)p;            p += (size_t)NB * NS * ND * 2;
    u16* Kh = (u16*)p;            p += (size_t)NB * NS * ND * 2;
    u16* Vh = (u16*)p;            p += (size_t)NB * NS * ND * 2;
    u16* CCb = (u16*)p;           p += (size_t)NB * NS * ND * 2;

    const int n4_in = NB * NS * ND / 4;  // 1048576
    const int n4_w = ND * ND / 4;        // 262144

    hipLaunchKernelGGL(mask_combine_kernel, dim3(4096), dim3(256), 0, stream, am, cm, CB);

    CvtArgs ci;
    ci.s[0] = q;  ci.d[0] = qb;
    ci.s[1] = k;  ci.d[1] = kb_;
    ci.s[2] = v;  ci.d[2] = vb_;
    ci.s[3] = q;  ci.d[3] = qb;  // unused slot
    hipLaunchKernelGGL(f2b_multi, dim3(n4_in / 256, 3), dim3(256), 0, stream, ci);

    CvtArgs cw;
    cw.s[0] = Wq; cw.d[0] = Wqb;
    cw.s[1] = Wk; cw.d[1] = Wkb;
    cw.s[2] = Wv; cw.d[2] = Wvb;
    cw.s[3] = Wo; cw.d[3] = Wob;
    hipLaunchKernelGGL(f2b_multi, dim3(n4_w / 256, 4), dim3(256), 0, stream, cw);

    MMArgs mq = {qb, Wqb, bq, (void*)Qh};
    MMArgs mk = {kb_, Wkb, bk, (void*)Kh};
    MMArgs mv = {vb_, Wvb, bv, (void*)Vh};
    hipLaunchKernelGGL((mm_glds<128, 1>), dim3(ND / 128, 4096 / 128, 3), dim3(256), 0, stream,
                       mq, mk, mv);

    hipLaunchKernelGGL(flash_mfma, dim3(NS / 64, NB * NH), dim3(256), 0, stream,
                       (const bf16_t*)Qh, (const bf16_t*)Kh, (const bf16_t*)Vh, CB, attn_out,
                       CCb);

    MMArgs mo = {CCb, Wob, bo, (void*)out};
    hipLaunchKernelGGL((mm_glds<64, 0>), dim3(ND / 64, 4096 / 128, 1), dim3(256), 0, stream,
                       mo, mo, mo);
}